// Round 9
// baseline (336.412 us; speedup 1.0000x reference)
//
#include <hip/hip_runtime.h>
#include <math.h>

#define NTOK 4096
#define CCH  64
#define LOG2E 1.4426950408889634f
#define NSPLIT 2   // KV-split ways

typedef __attribute__((ext_vector_type(8)))  short bf16x8;   // 8 bf16 = 4 VGPRs
typedef __attribute__((ext_vector_type(4)))  float f32x4;
typedef __attribute__((ext_vector_type(16))) float f32x16;
typedef __attribute__((ext_vector_type(2)))  unsigned int uint32x2;

__device__ __forceinline__ unsigned short f2bf_rne(float f) {
    unsigned int u = __float_as_uint(f);
    u += 0x7FFFu + ((u >> 16) & 1u);
    return (unsigned short)(u >> 16);
}
__device__ __forceinline__ float bf2f(unsigned short u) {
    return __uint_as_float(((unsigned int)u) << 16);
}

// ---------------------------------------------------------------------------
// Session ledger (keep):
//   r1/r2: V direct-from-global        -> FETCH ~260MB  FAILED (L2 collapse)
//   r3: dbuf, 3 blk/CU (backfill)      -> FETCH 155MB   FAILED
//   r4: agent-scope fused combine      -> WRITE 507MB   FAILED (L2 bypass)
//   r5: restore r0                     -> 125.3us OK
//   r6: NSPLIT 4->2, zero backfill     -> 123.3us WIN (FETCH 5.7MB)
//   r7: proj 8-wave/float4             -> 121.8us small win
//   r8: NSPLIT=1 + fused epilogue      -> 128.8us FAILED-NET: attn 49->56.7
//       (TLP loss), but residual UNCHANGED (72.1 vs 70.6) with one kernel
//       deleted => ~71us residual is fixed harness cost + proj; kernel-count
//       and combine are NOT the lever. Attn equilibrium held (FETCH 7.5MB).
// Occupancy sweep (24/16/8 waves/CU -> 52.6/49.0/56.7us) + 5.5% HBM =>
// attn is bound by the per-block BARRIER-TO-BARRIER SERIAL CHAIN, which
// scales with per-wave work per iteration.
// r9: 512-thread attn blocks (8 waves). Wave owns (m-quadrant, kv-half):
// per-wave per-iter work halves (2 QK + 8 exp + 2 PV MFMAs); partial oacc
// reduced once at end via LDS scratch. Per-CU pipe work identical; TLP
// 32 waves/CU; zero backfill (4 blk/CU x 512 thr = 2048 = max). All
// equilibrium invariants kept. proj/combine byte-identical to r7.
// Go/no-go: attn <= 49us AND FETCH <= 30MB, else restore r7.
// ---------------------------------------------------------------------------

// ---------------------------------------------------------------------------
// Kernel 1: MFMA projections (r7 proven, unchanged). 8 waves, float4 staging.
// ---------------------------------------------------------------------------
__global__ __launch_bounds__(512) void proj_kernel(
    const float* __restrict__ x,
    const float* __restrict__ wq, const float* __restrict__ bq,
    const float* __restrict__ wk, const float* __restrict__ bk,
    const float* __restrict__ wv, const float* __restrict__ bv,
    unsigned short* __restrict__ qt, unsigned short* __restrict__ kt,
    unsigned short* __restrict__ vbf)
{
    __shared__ unsigned short xsb[64 * 68];  // [n][c] bf16 (B^T storage)
    __shared__ unsigned short wa[80 * 68];   // [m][c] bf16 (A storage)
    __shared__ unsigned short vtmp[64 * 66]; // [c][sigma(n)]
    __shared__ float bb[80];

    const int t  = threadIdx.x;
    const int b  = blockIdx.x >> 6;
    const int n0 = (blockIdx.x & 63) << 6;

    const int lane = t & 63;
    const int w    = t >> 6;          // 0..7
    const int l15  = lane & 15;
    const int g    = lane >> 4;
    const int nt   = w & 3;           // n-tile for MFMA phase

    #pragma unroll
    for (int r = 0; r < 2; ++r) {
        const int i  = t + 512 * r;          // f4 index 0..1023
        const int c  = i >> 4;               // 0..63
        const int nq = (i & 15) * 4;         // n offset 0..60
        const float4 xv = *(const float4*)&x[((size_t)(b * CCH + c)) * NTOK + n0 + nq];
        xsb[(nq + 0) * 68 + c] = f2bf_rne(xv.x);
        xsb[(nq + 1) * 68 + c] = f2bf_rne(xv.y);
        xsb[(nq + 2) * 68 + c] = f2bf_rne(xv.z);
        xsb[(nq + 3) * 68 + c] = f2bf_rne(xv.w);
    }
    #pragma unroll
    for (int r = 0; r < 2; ++r) {
        const int i  = t + 512 * r;
        const int m  = i >> 4;
        const int cq = (i & 15) * 4;
        const float4 v = *(const float4*)&wv[i * 4];
        const unsigned int lo = (unsigned int)f2bf_rne(v.x) | ((unsigned int)f2bf_rne(v.y) << 16);
        const unsigned int hi = (unsigned int)f2bf_rne(v.z) | ((unsigned int)f2bf_rne(v.w) << 16);
        *(uint32x2*)&wa[m * 68 + cq] = (uint32x2){lo, hi};
    }
    if (t < 256) {
        const int half = t >> 7;             // 0: wq, 1: wk
        const int j    = t & 127;            // f4 index 0..127
        const int m    = 64 + half * 8 + (j >> 4);
        const int cq   = (j & 15) * 4;
        const float* src = half ? wk : wq;
        const float  sc  = half ? 1.f : LOG2E;
        const float4 v = *(const float4*)&src[j * 4];
        const unsigned int lo = (unsigned int)f2bf_rne(v.x * sc) | ((unsigned int)f2bf_rne(v.y * sc) << 16);
        const unsigned int hi = (unsigned int)f2bf_rne(v.z * sc) | ((unsigned int)f2bf_rne(v.w * sc) << 16);
        *(uint32x2*)&wa[m * 68 + cq] = (uint32x2){lo, hi};
    } else if (t < 336) {
        const int j = t - 256;               // 0..79
        float bias;
        if (j < 64)      bias = bv[j];
        else if (j < 72) bias = bq[j - 64] * LOG2E;
        else             bias = bk[j - 72];
        bb[j] = bias;
    }
    __syncthreads();

    const int mtbase = (w < 4) ? 0 : 3;
    const int nmt    = (w < 4) ? 3 : 2;
    f32x4 acc[3];
    #pragma unroll
    for (int j = 0; j < 3; ++j) acc[j] = (f32x4){0.f, 0.f, 0.f, 0.f};
    #pragma unroll
    for (int kc = 0; kc < 2; ++kc) {
        const bf16x8 bx = *(const bf16x8*)&xsb[(nt * 16 + l15) * 68 + kc * 32 + g * 8];
        #pragma unroll
        for (int j = 0; j < 3; ++j) {
            if (j < nmt) {
                const bf16x8 aw = *(const bf16x8*)&wa[((mtbase + j) * 16 + l15) * 68 + kc * 32 + g * 8];
                acc[j] = __builtin_amdgcn_mfma_f32_16x16x32_bf16(aw, bx, acc[j], 0, 0, 0);
            }
        }
    }

    #pragma unroll
    for (int j = 0; j < 3; ++j) {
        if (j < nmt) {
            const int mt = mtbase + j;
            if (mt < 4) {
                #pragma unroll
                for (int r = 0; r < 4; ++r) {
                    const int c = mt * 16 + g * 4 + r;
                    vtmp[c * 66 + 4 * l15 + nt] = f2bf_rne(acc[j][r] + bb[c]);
                }
            } else {   // mt == 4: q/k rows
                unsigned short vals[4];
                #pragma unroll
                for (int r = 0; r < 4; ++r)
                    vals[r] = f2bf_rne(acc[j][r] + bb[64 + g * 4 + r]);
                const unsigned int lo = (unsigned int)vals[0] | ((unsigned int)vals[1] << 16);
                const unsigned int hi = (unsigned int)vals[2] | ((unsigned int)vals[3] << 16);
                const int n = nt * 16 + l15;
                unsigned short* dst = ((g < 2) ? qt : kt) +
                                      ((size_t)(b * NTOK + n0 + n)) * 8 + (g & 1) * 4;
                *(uint32x2*)dst = (uint32x2){lo, hi};
            }
        }
    }
    __syncthreads();

    {
        const int c   = t >> 3;              // 0..63
        const int seg = t & 7;               // 8-token segment
        unsigned short* dst = vbf + ((size_t)(b * CCH + c)) * NTOK + n0 + seg * 8;
        *(bf16x8*)dst = *(const bf16x8*)&vtmp[c * 66 + seg * 8];
    }
}

// ---------------------------------------------------------------------------
// Kernel 2: MFMA flash attention, NSPLIT=2, 512 threads / 8 waves.
// Wave w: m-quadrant mt=w&3, kv-half hp=w>>2. Same 2-barrier lockstep, same
// LDS tiles (vs|ps in one 22528B buffer -> 4 blocks/CU, zero backfill), same
// bid%8 XCD decode, plain stores. Per-wave per-iter: 2 QK MFMA + 8 exp +
// 2 packed ps stores + 2 PV MFMA (K-half); oacc partials + row-sum partials
// reduced once at the end via LDS scratch (post-loop, 2 extra barriers).
// ---------------------------------------------------------------------------
__global__ __launch_bounds__(512, 8) void attn_kernel(
    const unsigned short* __restrict__ qt, const unsigned short* __restrict__ kt,
    const unsigned short* __restrict__ vbf,
    unsigned short* __restrict__ opart, float* __restrict__ lpart, int B)
{
    __shared__ unsigned short lds[2 * 64 * 88];   // vs | ps
    unsigned short* vs = lds;
    unsigned short* ps = lds + 64 * 88;

    const int t    = threadIdx.x;
    const int lane = t & 63;
    const int w    = t >> 6;                  // 0..7
    const int bid  = blockIdx.x;
    const int b    = bid % B;                 // == bid & 7 for B=8 -> XCD id
    const int p    = (bid / B) % NSPLIT;
    const int m0   = (bid / (B * NSPLIT)) << 6;

    const int l15 = lane & 15;
    const int g   = lane >> 4;
    const int l31 = lane & 31;
    const int h   = lane >> 5;
    const int mt  = w & 3;                    // m-tile (QK) / output quadrant (PV)
    const int hp  = w >> 2;                   // kv-half

    const int NIT     = 64 / NSPLIT;          // 32 KV tiles per block
    const int itStart = p * NIT;

    // ---- Q A-fragment (rows mt*16..+15), g==0 lanes only ----
    bf16x8 a_q = {};
    if (g == 0)
        a_q = *(const bf16x8*)&qt[((size_t)(b * NTOK + m0 + mt * 16 + l15)) * 8];

    // ---- V staging: one 16B chunk per thread (512 thr cover 64x64) ----
    const int c0 = t >> 3, seg = t & 7;
    const unsigned short* vsrc0 = vbf + ((size_t)(b * CCH + c0)) * NTOK
                                      + itStart * 64 + seg * 8;
    unsigned short* vdst0 = &vs[c0 * 88 + seg * 8];

    // ---- K: wave loads its 2 kv tiles (2hp, 2hp+1); g==0 lanes ----
    const unsigned short* ksrc = kt +
        ((size_t)(b * NTOK + itStart * 64 + hp * 32 + l15)) * 8;

    // ---- prefetch iteration 0 ----
    bf16x8 vreg0 = *(const bf16x8*)vsrc0;
    bf16x8 kr0 = {}, kr1 = {};
    if (g == 0) {
        kr0 = *(const bf16x8*)(ksrc);
        kr1 = *(const bf16x8*)(ksrc + 128);   // +16 tokens * 8
    }

    f32x16 oacc;
    #pragma unroll
    for (int i = 0; i < 16; ++i) oacc[i] = 0.f;
    float rs0 = 0.f, rs1 = 0.f, rs2 = 0.f, rs3 = 0.f;

    const int crow = ((mt >> 1) * 32 + l31) * 88;
    const int mrow = ((mt & 1) * 32 + l31) * 88;

    for (int it = 0; it < NIT; ++it) {
        __syncthreads();   // prev PV done reading vs/ps

        // ---- commit prefetched V tile to LDS ----
        *(bf16x8*)vdst0 = vreg0;

        // ---- S = Q·K^T for this wave's 2 kv tiles ----
        const f32x4 z = {0.f, 0.f, 0.f, 0.f};
        f32x4 s0 = __builtin_amdgcn_mfma_f32_16x16x32_bf16(a_q, kr0, z, 0, 0, 0);
        f32x4 s1 = __builtin_amdgcn_mfma_f32_16x16x32_bf16(a_q, kr1, z, 0, 0, 0);

        // ---- prefetch next iteration's V + K ----
        if (it + 1 < NIT) {
            vsrc0 += 64;  ksrc += 64 * 8;
            vreg0 = *(const bf16x8*)vsrc0;
            if (g == 0) {
                kr0 = *(const bf16x8*)(ksrc);
                kr1 = *(const bf16x8*)(ksrc + 128);
            }
        }

        // ---- P = exp2(S); pack pair (tile 2hp, 2hp+1) -> n' = 4*l15+2hp+{0,1} ----
        #pragma unroll
        for (int r = 0; r < 4; ++r) {
            const float p0 = __builtin_amdgcn_exp2f(s0[r]);
            const float p1 = __builtin_amdgcn_exp2f(s1[r]);
            const unsigned int lo = __builtin_amdgcn_perm(
                __float_as_uint(p1), __float_as_uint(p0), 0x07060302u);
            *(unsigned int*)&ps[(mt * 16 + g * 4 + r) * 88 + 4 * l15 + 2 * hp] = lo;
            const float ssum = p0 + p1;
            if      (r == 0) rs0 += ssum;
            else if (r == 1) rs1 += ssum;
            else if (r == 2) rs2 += ssum;
            else             rs3 += ssum;
        }
        __syncthreads();   // vs + ps ready

        // ---- O^T partial += V·P^T over this wave's K-half (2 MFMAs) ----
        {
            const int kc0 = hp * 2;
            const bf16x8 av0 = *(const bf16x8*)&vs[crow + kc0 * 16 + h * 8];
            const bf16x8 bp0 = *(const bf16x8*)&ps[mrow + kc0 * 16 + h * 8];
            oacc = __builtin_amdgcn_mfma_f32_32x32x16_bf16(av0, bp0, oacc, 0, 0, 0);
            const bf16x8 av1 = *(const bf16x8*)&vs[crow + (kc0 + 1) * 16 + h * 8];
            const bf16x8 bp1 = *(const bf16x8*)&ps[mrow + (kc0 + 1) * 16 + h * 8];
            oacc = __builtin_amdgcn_mfma_f32_32x32x16_bf16(av1, bp1, oacc, 0, 0, 0);
        }
    }

    // ---- reduce rs within wave over the 16-lane groups ----
    #pragma unroll
    for (int xm = 1; xm <= 8; xm <<= 1) {
        rs0 += __shfl_xor(rs0, xm);
        rs1 += __shfl_xor(rs1, xm);
        rs2 += __shfl_xor(rs2, xm);
        rs3 += __shfl_xor(rs3, xm);
    }

    // ---- cross-pair reduction (wave mt,hp=1 -> wave mt,hp=0) via LDS scratch ----
    __syncthreads();                 // all PV reads of vs/ps complete
    float* scr = (float*)lds;        // 5632 floats available; use 4160
    if (hp == 1) {
        #pragma unroll
        for (int r = 0; r < 16; ++r)
            scr[mt * 1024 + r * 64 + lane] = oacc[r];
        if (l15 == 0) {
            const int row = mt * 16 + g * 4;
            scr[4096 + row + 0] = rs0;
            scr[4096 + row + 1] = rs1;
            scr[4096 + row + 2] = rs2;
            scr[4096 + row + 3] = rs3;
        }
    }
    __syncthreads();
    if (hp == 0) {
        #pragma unroll
        for (int r = 0; r < 16; ++r)
            oacc[r] += scr[mt * 1024 + r * 64 + lane];
        if (l15 == 0) {
            const int row = mt * 16 + g * 4;
            float* lp = lpart + (size_t)(p * B + b) * NTOK + m0 + row;
            lp[0] = rs0 + scr[4096 + row + 0];
            lp[1] = rs1 + scr[4096 + row + 1];
            lp[2] = rs2 + scr[4096 + row + 2];
            lp[3] = rs3 + scr[4096 + row + 3];
        }
        const int mloc = (mt & 1) * 32 + l31;
        #pragma unroll
        for (int reg = 0; reg < 16; ++reg) {
            const int c = (mt >> 1) * 32 + (reg & 3) + 8 * (reg >> 2) + 4 * h;
            opart[((size_t)((p * B + b) * CCH + c)) * NTOK + m0 + mloc] =
                f2bf_rne(oacc[reg]);
        }
    }
}

// ---------------------------------------------------------------------------
// Kernel 3: combine NSPLIT partials + normalize + residual (r6/r7 proven).
// ---------------------------------------------------------------------------
__global__ __launch_bounds__(256) void combine_kernel(
    const unsigned short* __restrict__ opart, const float* __restrict__ lpart,
    const float* __restrict__ x, const float* __restrict__ gamma_p,
    float* __restrict__ out, int B)
{
    const float  gm      = gamma_p[0];
    const size_t nf4     = (size_t)B * CCH * NTOK / 4;
    const size_t ostride = (size_t)B * CCH * NTOK;
    for (size_t f = (size_t)blockIdx.x * 256 + threadIdx.x; f < nf4;
         f += (size_t)gridDim.x * 256) {
        const int m4 = ((int)(f & 1023)) * 4;
        const int bc = (int)(f >> 10);
        const int bi = bc >> 6;
        const size_t obase = (size_t)bc * NTOK + m4;

        float4 osum = {0.f, 0.f, 0.f, 0.f};
        float4 lsum = {0.f, 0.f, 0.f, 0.f};
        #pragma unroll
        for (int p = 0; p < NSPLIT; ++p) {
            const ushort4 o = *(const ushort4*)&opart[obase + (size_t)p * ostride];
            const float4  l = *(const float4*)&lpart[(size_t)(p * B + bi) * NTOK + m4];
            osum.x += bf2f(o.x); osum.y += bf2f(o.y);
            osum.z += bf2f(o.z); osum.w += bf2f(o.w);
            lsum.x += l.x; lsum.y += l.y; lsum.z += l.z; lsum.w += l.w;
        }
        const float4 xv = *(const float4*)&x[obase];
        float4 r;
        r.x = osum.x * gm / lsum.x + xv.x;
        r.y = osum.y * gm / lsum.y + xv.y;
        r.z = osum.z * gm / lsum.z + xv.z;
        r.w = osum.w * gm / lsum.w + xv.w;
        *(float4*)&out[obase] = r;
    }
}

extern "C" void kernel_launch(void* const* d_in, const int* in_sizes, int n_in,
                              void* d_out, int out_size, void* d_ws, size_t ws_size,
                              hipStream_t stream) {
    const float* x     = (const float*)d_in[0];
    const float* wq    = (const float*)d_in[1];
    const float* bq    = (const float*)d_in[2];
    const float* wk    = (const float*)d_in[3];
    const float* bk    = (const float*)d_in[4];
    const float* wv    = (const float*)d_in[5];
    const float* bv    = (const float*)d_in[6];
    const float* gamma = (const float*)d_in[7];
    float* out = (float*)d_out;

    int B = in_sizes[0] / (CCH * NTOK);   // 8

    // Workspace: qt | kt (512KB each) | vbf 4MB | opart bf16 8MB | lpart 256KB
    unsigned short* wsp   = (unsigned short*)d_ws;
    unsigned short* qt    = wsp;
    unsigned short* kt    = qt + (size_t)B * NTOK * 8;
    unsigned short* vbf   = kt + (size_t)B * NTOK * 8;
    unsigned short* opart = vbf + (size_t)B * CCH * NTOK;
    float*          lpart = (float*)(opart + (size_t)NSPLIT * B * CCH * NTOK);

    proj_kernel<<<B * 64, 512, 0, stream>>>(x, wq, bq, wk, bk, wv, bv, qt, kt, vbf);
    attn_kernel<<<NSPLIT * B * 64, 512, 0, stream>>>(qt, kt, vbf, opart, lpart, B);
    combine_kernel<<<1024, 256, 0, stream>>>(opart, lpart, x, gamma, out, B);
}

// Round 10
// 121.218 us; speedup vs baseline: 2.7753x; 2.7753x over previous
//
#include <hip/hip_runtime.h>
#include <math.h>

#define NTOK 4096
#define CCH  64
#define LOG2E 1.4426950408889634f
#define NSPLIT 2   // KV-split ways

typedef __attribute__((ext_vector_type(8)))  short bf16x8;   // 8 bf16 = 4 VGPRs
typedef __attribute__((ext_vector_type(4)))  float f32x4;
typedef __attribute__((ext_vector_type(16))) float f32x16;
typedef __attribute__((ext_vector_type(2)))  unsigned int uint32x2;

__device__ __forceinline__ unsigned short f2bf_rne(float f) {
    unsigned int u = __float_as_uint(f);
    u += 0x7FFFu + ((u >> 16) & 1u);
    return (unsigned short)(u >> 16);
}
__device__ __forceinline__ float bf2f(unsigned short u) {
    return __uint_as_float(((unsigned int)u) << 16);
}

// ---------------------------------------------------------------------------
// Session ledger (final):
//   r1/r2: V direct-from-global        -> FETCH ~260MB  FAILED (L2 collapse)
//   r3: dbuf, 3 blk/CU (backfill)      -> FETCH 155MB   FAILED
//   r4: agent-scope fused combine      -> WRITE 507MB   FAILED (L2 bypass)
//   r5: restore r0                     -> 125.3us OK
//   r6: NSPLIT 4->2, zero backfill     -> 123.3us WIN (FETCH 5.7MB)
//   r7: proj 8-wave/float4             -> 121.8us WIN  <== BEST VERIFIED
//   r8: NSPLIT=1 + fused epilogue      -> 128.8us FAILED-NET (attn TLP loss;
//       residual unchanged => kernel count is not the lever)
//   r9: 512-thr attn (m x kv-half)     -> 336us FAILED (L2 collapse + 2.1M
//       bank conflicts + 31ms straggler dispatch)
// LAW (5 independent confirmations): the attn kernel's 49us = a fragile
// XCD-L2 reuse equilibrium requiring JOINTLY: 256-thr blocks, LDS-staged V
// via the exact vs/ps layouts, 2-barrier lockstep, plain stores, bid%8 XCD
// decode, zero-backfill grid (<=4 blk/CU x 256thr). Any restructure of any
// one axis collapses FETCH to the ~300MB unique-footprint bound.
// This file restores r7 verbatim. attn: DO NOT PERTURB.
// ---------------------------------------------------------------------------

// ---------------------------------------------------------------------------
// Kernel 1: MFMA projections (r7 proven). 8 waves, float4 staging.
// One GEMM per (b, 64-token tile): D[80x64] = [wv ; wq*log2e ; wk] * x_tile.
// Outputs qt/kt[b][n][8] (q pre-scaled by log2e) and
// vbf[b][c][tile*64 + sigma(nu)], sigma(nu) = 4*(nu&15) + (nu>>4).
// ---------------------------------------------------------------------------
__global__ __launch_bounds__(512) void proj_kernel(
    const float* __restrict__ x,
    const float* __restrict__ wq, const float* __restrict__ bq,
    const float* __restrict__ wk, const float* __restrict__ bk,
    const float* __restrict__ wv, const float* __restrict__ bv,
    unsigned short* __restrict__ qt, unsigned short* __restrict__ kt,
    unsigned short* __restrict__ vbf)
{
    __shared__ unsigned short xsb[64 * 68];  // [n][c] bf16 (B^T storage)
    __shared__ unsigned short wa[80 * 68];   // [m][c] bf16 (A storage)
    __shared__ unsigned short vtmp[64 * 66]; // [c][sigma(n)]
    __shared__ float bb[80];

    const int t  = threadIdx.x;
    const int b  = blockIdx.x >> 6;
    const int n0 = (blockIdx.x & 63) << 6;

    const int lane = t & 63;
    const int w    = t >> 6;          // 0..7
    const int l15  = lane & 15;
    const int g    = lane >> 4;
    const int nt   = w & 3;           // n-tile for MFMA phase

    #pragma unroll
    for (int r = 0; r < 2; ++r) {
        const int i  = t + 512 * r;          // f4 index 0..1023
        const int c  = i >> 4;               // 0..63
        const int nq = (i & 15) * 4;         // n offset 0..60
        const float4 xv = *(const float4*)&x[((size_t)(b * CCH + c)) * NTOK + n0 + nq];
        xsb[(nq + 0) * 68 + c] = f2bf_rne(xv.x);
        xsb[(nq + 1) * 68 + c] = f2bf_rne(xv.y);
        xsb[(nq + 2) * 68 + c] = f2bf_rne(xv.z);
        xsb[(nq + 3) * 68 + c] = f2bf_rne(xv.w);
    }
    #pragma unroll
    for (int r = 0; r < 2; ++r) {
        const int i  = t + 512 * r;
        const int m  = i >> 4;
        const int cq = (i & 15) * 4;
        const float4 v = *(const float4*)&wv[i * 4];
        const unsigned int lo = (unsigned int)f2bf_rne(v.x) | ((unsigned int)f2bf_rne(v.y) << 16);
        const unsigned int hi = (unsigned int)f2bf_rne(v.z) | ((unsigned int)f2bf_rne(v.w) << 16);
        *(uint32x2*)&wa[m * 68 + cq] = (uint32x2){lo, hi};
    }
    if (t < 256) {
        const int half = t >> 7;             // 0: wq, 1: wk
        const int j    = t & 127;            // f4 index 0..127
        const int m    = 64 + half * 8 + (j >> 4);
        const int cq   = (j & 15) * 4;
        const float* src = half ? wk : wq;
        const float  sc  = half ? 1.f : LOG2E;
        const float4 v = *(const float4*)&src[j * 4];
        const unsigned int lo = (unsigned int)f2bf_rne(v.x * sc) | ((unsigned int)f2bf_rne(v.y * sc) << 16);
        const unsigned int hi = (unsigned int)f2bf_rne(v.z * sc) | ((unsigned int)f2bf_rne(v.w * sc) << 16);
        *(uint32x2*)&wa[m * 68 + cq] = (uint32x2){lo, hi};
    } else if (t < 336) {
        const int j = t - 256;               // 0..79
        float bias;
        if (j < 64)      bias = bv[j];
        else if (j < 72) bias = bq[j - 64] * LOG2E;
        else             bias = bk[j - 72];
        bb[j] = bias;
    }
    __syncthreads();

    const int mtbase = (w < 4) ? 0 : 3;
    const int nmt    = (w < 4) ? 3 : 2;
    f32x4 acc[3];
    #pragma unroll
    for (int j = 0; j < 3; ++j) acc[j] = (f32x4){0.f, 0.f, 0.f, 0.f};
    #pragma unroll
    for (int kc = 0; kc < 2; ++kc) {
        const bf16x8 bx = *(const bf16x8*)&xsb[(nt * 16 + l15) * 68 + kc * 32 + g * 8];
        #pragma unroll
        for (int j = 0; j < 3; ++j) {
            if (j < nmt) {
                const bf16x8 aw = *(const bf16x8*)&wa[((mtbase + j) * 16 + l15) * 68 + kc * 32 + g * 8];
                acc[j] = __builtin_amdgcn_mfma_f32_16x16x32_bf16(aw, bx, acc[j], 0, 0, 0);
            }
        }
    }

    #pragma unroll
    for (int j = 0; j < 3; ++j) {
        if (j < nmt) {
            const int mt = mtbase + j;
            if (mt < 4) {
                #pragma unroll
                for (int r = 0; r < 4; ++r) {
                    const int c = mt * 16 + g * 4 + r;
                    vtmp[c * 66 + 4 * l15 + nt] = f2bf_rne(acc[j][r] + bb[c]);
                }
            } else {   // mt == 4: q/k rows
                unsigned short vals[4];
                #pragma unroll
                for (int r = 0; r < 4; ++r)
                    vals[r] = f2bf_rne(acc[j][r] + bb[64 + g * 4 + r]);
                const unsigned int lo = (unsigned int)vals[0] | ((unsigned int)vals[1] << 16);
                const unsigned int hi = (unsigned int)vals[2] | ((unsigned int)vals[3] << 16);
                const int n = nt * 16 + l15;
                unsigned short* dst = ((g < 2) ? qt : kt) +
                                      ((size_t)(b * NTOK + n0 + n)) * 8 + (g & 1) * 4;
                *(uint32x2*)dst = (uint32x2){lo, hi};
            }
        }
    }
    __syncthreads();

    {
        const int c   = t >> 3;              // 0..63
        const int seg = t & 7;               // 8-token segment
        unsigned short* dst = vbf + ((size_t)(b * CCH + c)) * NTOK + n0 + seg * 8;
        *(bf16x8*)dst = *(const bf16x8*)&vtmp[c * 66 + seg * 8];
    }
}

// ---------------------------------------------------------------------------
// Kernel 2: MFMA flash attention, KV-split NSPLIT=2 — the equilibrium kernel
// (r6/r7 verified: 49-51us, FETCH 5.7MB). 2 barriers/iter, single-buffered
// vs/ps, register prefetch, plain stores, bid%8 == b == XCD decode, grid
// 1024 = 4 blocks/CU all co-resident, NIT=32. DO NOT PERTURB.
// ---------------------------------------------------------------------------
__global__ __launch_bounds__(256, 6) void attn_kernel(
    const unsigned short* __restrict__ qt, const unsigned short* __restrict__ kt,
    const unsigned short* __restrict__ vbf,
    unsigned short* __restrict__ opart, float* __restrict__ lpart, int B)
{
    __shared__ unsigned short vs[64 * 88];  // [c][n'] pre-permuted
    __shared__ unsigned short ps[64 * 88];  // [m][n'] bf16 P

    const int t    = threadIdx.x;
    const int lane = t & 63;
    const int w    = t >> 6;
    const int bid  = blockIdx.x;
    const int b    = bid % B;                 // == bid & 7 for B=8 -> XCD id
    const int p    = (bid / B) % NSPLIT;
    const int m0   = (bid / (B * NSPLIT)) << 6;

    const int l15 = lane & 15;
    const int g   = lane >> 4;
    const int l31 = lane & 31;
    const int h   = lane >> 5;

    const int NIT     = 64 / NSPLIT;        // 32 KV tiles per block
    const int itStart = p * NIT;

    // ---- Q A-fragment direct from global (k>=8 rows zero) ----
    bf16x8 a_q = {};
    if (g == 0)
        a_q = *(const bf16x8*)&qt[((size_t)(b * NTOK + m0 + w * 16 + l15)) * 8];

    // ---- per-thread V staging pointers (two 16B chunks per thread) ----
    const int c0  = t >> 3, seg = t & 7;
    const int c1  = c0 + 32;
    const unsigned short* vsrc0 = vbf + ((size_t)(b * CCH + c0)) * NTOK
                                      + itStart * 64 + seg * 8;
    const unsigned short* vsrc1 = vbf + ((size_t)(b * CCH + c1)) * NTOK
                                      + itStart * 64 + seg * 8;
    unsigned short* vdst0 = &vs[c0 * 88 + seg * 8];
    unsigned short* vdst1 = &vs[c1 * 88 + seg * 8];

    // ---- K fragment source (only g==0 lanes load; others stay zero) ----
    const unsigned short* ksrc = kt + ((size_t)(b * NTOK + itStart * 64 + l15)) * 8;

    // ---- prefetch iteration 0 ----
    bf16x8 vreg0 = *(const bf16x8*)vsrc0;
    bf16x8 vreg1 = *(const bf16x8*)vsrc1;
    bf16x8 kr0 = {}, kr1 = {}, kr2 = {}, kr3 = {};
    if (g == 0) {
        kr0 = *(const bf16x8*)(ksrc);
        kr1 = *(const bf16x8*)(ksrc + 128);   // +16 tokens * 8
        kr2 = *(const bf16x8*)(ksrc + 256);
        kr3 = *(const bf16x8*)(ksrc + 384);
    }

    f32x16 oacc;
    #pragma unroll
    for (int i = 0; i < 16; ++i) oacc[i] = 0.f;
    float rs0 = 0.f, rs1 = 0.f, rs2 = 0.f, rs3 = 0.f;

    const int crow = ((w >> 1) * 32 + l31) * 88;
    const int mrow = ((w & 1) * 32 + l31) * 88;

    for (int it = 0; it < NIT; ++it) {
        __syncthreads();   // prev PV done reading vs/ps

        // ---- commit prefetched V tile to LDS (loaded one iteration ago) ----
        *(bf16x8*)vdst0 = vreg0;
        *(bf16x8*)vdst1 = vreg1;

        // ---- S = Q·K^T with current K regs ----
        const f32x4 z = {0.f, 0.f, 0.f, 0.f};
        f32x4 s0 = __builtin_amdgcn_mfma_f32_16x16x32_bf16(a_q, kr0, z, 0, 0, 0);
        f32x4 s1 = __builtin_amdgcn_mfma_f32_16x16x32_bf16(a_q, kr1, z, 0, 0, 0);
        f32x4 s2 = __builtin_amdgcn_mfma_f32_16x16x32_bf16(a_q, kr2, z, 0, 0, 0);
        f32x4 s3 = __builtin_amdgcn_mfma_f32_16x16x32_bf16(a_q, kr3, z, 0, 0, 0);

        // ---- prefetch next iteration's V + K into registers ----
        if (it + 1 < NIT) {
            vsrc0 += 64;  vsrc1 += 64;  ksrc += 64 * 8;
            vreg0 = *(const bf16x8*)vsrc0;
            vreg1 = *(const bf16x8*)vsrc1;
            if (g == 0) {
                kr0 = *(const bf16x8*)(ksrc);
                kr1 = *(const bf16x8*)(ksrc + 128);
                kr2 = *(const bf16x8*)(ksrc + 256);
                kr3 = *(const bf16x8*)(ksrc + 384);
            }
        }

        // ---- P = exp2(S) (q carries log2e), raw v_exp_f32 ----
        #pragma unroll
        for (int r = 0; r < 4; ++r) {
            const float p0 = __builtin_amdgcn_exp2f(s0[r]);
            const float p1 = __builtin_amdgcn_exp2f(s1[r]);
            const float p2 = __builtin_amdgcn_exp2f(s2[r]);
            const float p3 = __builtin_amdgcn_exp2f(s3[r]);
            const unsigned int lo = __builtin_amdgcn_perm(
                __float_as_uint(p1), __float_as_uint(p0), 0x07060302u);
            const unsigned int hi = __builtin_amdgcn_perm(
                __float_as_uint(p3), __float_as_uint(p2), 0x07060302u);
            *(uint32x2*)&ps[(w * 16 + g * 4 + r) * 88 + 4 * l15] = (uint32x2){lo, hi};
            const float ssum = (p0 + p1) + (p2 + p3);
            if      (r == 0) rs0 += ssum;
            else if (r == 1) rs1 += ssum;
            else if (r == 2) rs2 += ssum;
            else             rs3 += ssum;
        }
        __syncthreads();   // vs + ps ready

        // ---- O^T += V·P^T (4 MFMAs 32x32x16) ----
        #pragma unroll
        for (int kc = 0; kc < 4; ++kc) {
            const bf16x8 a_v = *(const bf16x8*)&vs[crow + kc * 16 + h * 8];
            const bf16x8 b_p = *(const bf16x8*)&ps[mrow + kc * 16 + h * 8];
            oacc = __builtin_amdgcn_mfma_f32_32x32x16_bf16(a_v, b_p, oacc, 0, 0, 0);
        }
    }

    #pragma unroll
    for (int xm = 1; xm <= 8; xm <<= 1) {
        rs0 += __shfl_xor(rs0, xm);
        rs1 += __shfl_xor(rs1, xm);
        rs2 += __shfl_xor(rs2, xm);
        rs3 += __shfl_xor(rs3, xm);
    }
    if (l15 == 0) {
        float* lp = lpart + (size_t)(p * B + b) * NTOK + m0 + w * 16 + g * 4;
        lp[0] = rs0; lp[1] = rs1; lp[2] = rs2; lp[3] = rs3;
    }
    {
        const int mloc = (w & 1) * 32 + l31;
        #pragma unroll
        for (int reg = 0; reg < 16; ++reg) {
            const int c = (w >> 1) * 32 + (reg & 3) + 8 * (reg >> 2) + 4 * h;
            opart[((size_t)((p * B + b) * CCH + c)) * NTOK + m0 + mloc] =
                f2bf_rne(oacc[reg]);
        }
    }
}

// ---------------------------------------------------------------------------
// Kernel 3: combine NSPLIT partials + normalize + residual (pure streaming).
// ---------------------------------------------------------------------------
__global__ __launch_bounds__(256) void combine_kernel(
    const unsigned short* __restrict__ opart, const float* __restrict__ lpart,
    const float* __restrict__ x, const float* __restrict__ gamma_p,
    float* __restrict__ out, int B)
{
    const float  gm      = gamma_p[0];
    const size_t nf4     = (size_t)B * CCH * NTOK / 4;
    const size_t ostride = (size_t)B * CCH * NTOK;
    for (size_t f = (size_t)blockIdx.x * 256 + threadIdx.x; f < nf4;
         f += (size_t)gridDim.x * 256) {
        const int m4 = ((int)(f & 1023)) * 4;
        const int bc = (int)(f >> 10);
        const int bi = bc >> 6;
        const size_t obase = (size_t)bc * NTOK + m4;

        float4 osum = {0.f, 0.f, 0.f, 0.f};
        float4 lsum = {0.f, 0.f, 0.f, 0.f};
        #pragma unroll
        for (int p = 0; p < NSPLIT; ++p) {
            const ushort4 o = *(const ushort4*)&opart[obase + (size_t)p * ostride];
            const float4  l = *(const float4*)&lpart[(size_t)(p * B + bi) * NTOK + m4];
            osum.x += bf2f(o.x); osum.y += bf2f(o.y);
            osum.z += bf2f(o.z); osum.w += bf2f(o.w);
            lsum.x += l.x; lsum.y += l.y; lsum.z += l.z; lsum.w += l.w;
        }
        const float4 xv = *(const float4*)&x[obase];
        float4 r;
        r.x = osum.x * gm / lsum.x + xv.x;
        r.y = osum.y * gm / lsum.y + xv.y;
        r.z = osum.z * gm / lsum.z + xv.z;
        r.w = osum.w * gm / lsum.w + xv.w;
        *(float4*)&out[obase] = r;
    }
}

extern "C" void kernel_launch(void* const* d_in, const int* in_sizes, int n_in,
                              void* d_out, int out_size, void* d_ws, size_t ws_size,
                              hipStream_t stream) {
    const float* x     = (const float*)d_in[0];
    const float* wq    = (const float*)d_in[1];
    const float* bq    = (const float*)d_in[2];
    const float* wk    = (const float*)d_in[3];
    const float* bk    = (const float*)d_in[4];
    const float* wv    = (const float*)d_in[5];
    const float* bv    = (const float*)d_in[6];
    const float* gamma = (const float*)d_in[7];
    float* out = (float*)d_out;

    int B = in_sizes[0] / (CCH * NTOK);   // 8

    // Workspace: qt | kt (512KB each) | vbf 4MB | opart bf16 8MB | lpart 256KB
    unsigned short* wsp   = (unsigned short*)d_ws;
    unsigned short* qt    = wsp;
    unsigned short* kt    = qt + (size_t)B * NTOK * 8;
    unsigned short* vbf   = kt + (size_t)B * NTOK * 8;
    unsigned short* opart = vbf + (size_t)B * CCH * NTOK;
    float*          lpart = (float*)(opart + (size_t)NSPLIT * B * CCH * NTOK);

    proj_kernel<<<B * 64, 512, 0, stream>>>(x, wq, bq, wk, bk, wv, bv, qt, kt, vbf);
    attn_kernel<<<NSPLIT * B * 64, 256, 0, stream>>>(qt, kt, vbf, opart, lpart, B);
    combine_kernel<<<1024, 256, 0, stream>>>(opart, lpart, x, gamma, out, B);
}